// Round 1
// baseline (3547.924 us; speedup 1.0000x reference)
//
#include <hip/hip_runtime.h>
#include <math.h>

#define DEV __device__ __forceinline__

constexpr int NN   = 50000;   // nodes
constexpr int EE   = 400000;  // edges
constexpr int RREL = 4;       // relations
// H=64, HEADS=4, OUT=64 -> 256 cols per transform
// KAN: K=8 bases, GPTS=12 grid points, ORDER=3

// ---------------- workspace layout (float offsets) ----------------
// XL   : 0          .. 12.8M   (N*256)   [reused later: X, Y1, Y2]
// XR   : 12.8M      .. 25.6M   (N*256)
// HMSG : 25.6M      .. 28.8M   (N*64)
// M    : 28.8M      .. 29.6M   (N*R*4)
// DEN  : 29.6M      .. 30.4M   (N*R*4)
// ELOG : 30.4M      .. 32.0M   (E*4)
// EIDS : 32.0M      .. 33.6M   (R*E ints)
// CNT  : 33.6M      (+64)
// GATE : 33.600064M (4), BIAS: 33.600128M (64), EBASE: 33.600192M (1024)
// W1T  : 33.601216M (73728), W2T: 33.674944M (73728)  -> total ~135 MB

DEV void atomicMaxF(float* addr, float val) {
    int iv = __float_as_int(val);
    if (iv >= 0) atomicMax((int*)addr, iv);
    else         atomicMin((unsigned int*)addr, __float_as_uint(val));
}

DEV float lrelu(float v) { return v >= 0.f ? v : 0.2f * v; }

// ---------------- prep kernels ----------------
__global__ void prep_small(const float* __restrict__ rel_gate,
                           const float* __restrict__ out_bias,
                           const float* __restrict__ rel_emb,
                           const float* __restrict__ We,
                           const float* __restrict__ be,
                           float* __restrict__ gate, float* __restrict__ biasvec,
                           float* __restrict__ ebase, int* __restrict__ cnt) {
    __shared__ float gs[4];
    int tid = threadIdx.x;
    if (tid < 4) cnt[tid] = 0;
    if (tid == 0) {
        float g0 = rel_gate[0], g1 = rel_gate[1], g2 = rel_gate[2], g3 = rel_gate[3];
        float mx = fmaxf(fmaxf(g0, g1), fmaxf(g2, g3));
        float e0 = expf(g0 - mx), e1 = expf(g1 - mx), e2 = expf(g2 - mx), e3 = expf(g3 - mx);
        float s = e0 + e1 + e2 + e3;
        gs[0] = e0 / s; gs[1] = e1 / s; gs[2] = e2 / s; gs[3] = e3 / s;
        gate[0] = gs[0]; gate[1] = gs[1]; gate[2] = gs[2]; gate[3] = gs[3];
    }
    __syncthreads();
    if (tid < 64) {
        float b = 0.f;
        for (int r = 0; r < 4; ++r) b += gs[r] * out_bias[r * 64 + tid];
        biasvec[tid] = b;
    }
    // ebase[r][j] = be[r][j] + sum_i rel_emb[r][i] * We[r][16+i][j]
    for (int r = 0; r < 4; ++r) {
        float v = be[r * 256 + tid];
        for (int i = 0; i < 8; ++i)
            v += rel_emb[r * 8 + i] * We[((size_t)(r * 24 + 16 + i)) * 256 + tid];
        ebase[r * 256 + tid] = v;
    }
}

__global__ void prep_wt(const float* __restrict__ bw1, const float* __restrict__ sw1,
                        const float* __restrict__ sc1,
                        const float* __restrict__ bw2, const float* __restrict__ sw2,
                        const float* __restrict__ sc2,
                        float* __restrict__ W1T, float* __restrict__ W2T) {
    int idx = blockIdx.x * blockDim.x + threadIdx.x;
    const int tot1 = 576 * 128;
    const int tot  = tot1 + 1152 * 64;
    for (; idx < tot; idx += gridDim.x * blockDim.x) {
        if (idx < tot1) {
            int d = idx / 128, f = idx % 128;
            float v;
            if (d < 64) v = bw1[f * 64 + d];
            else { int ii = (d - 64) >> 3, kk = (d - 64) & 7;
                   v = sw1[(f * 64 + ii) * 8 + kk] * sc1[f * 64 + ii]; }
            W1T[idx] = v;
        } else {
            int j = idx - tot1;
            int d = j / 64, f = j % 64;
            float v;
            if (d < 128) v = bw2[f * 128 + d];
            else { int ii = (d - 128) >> 3, kk = (d - 128) & 7;
                   v = sw2[(f * 128 + ii) * 8 + kk] * sc2[f * 128 + ii]; }
            W2T[j] = v;
        }
    }
}

__global__ void fill_init(float* __restrict__ hmsg, float* __restrict__ m,
                          float* __restrict__ den) {
    const int n1 = NN * 64, n2 = NN * 16;
    const int tot = n1 + n2 + n2;
    for (int i = blockIdx.x * blockDim.x + threadIdx.x; i < tot;
         i += gridDim.x * blockDim.x) {
        if (i < n1) hmsg[i] = 0.f;
        else if (i < n1 + n2) m[i - n1] = -3.402823466e38f;
        else den[i - n1 - n2] = 0.f;
    }
}

__global__ void bucket_fill(const int* __restrict__ etype, int* __restrict__ cnt,
                            int* __restrict__ eids) {
    int e = blockIdx.x * blockDim.x + threadIdx.x;
    if (e < EE) {
        int t = etype[e];
        int pos = atomicAdd(cnt + t, 1);
        eids[t * EE + pos] = e;
    }
}

// ---------------- per-relation node transforms ----------------
__global__ __launch_bounds__(256) void gemm_xlxr(
    const float* __restrict__ hin,
    const float* __restrict__ Wl, const float* __restrict__ bl,
    const float* __restrict__ Wr, const float* __restrict__ br,
    float* __restrict__ XL, float* __restrict__ XR) {
    __shared__ float hs[64 * 32];   // transposed: hs[k][row]
    int tid = threadIdx.x;
    int row0 = blockIdx.x * 32;
    int lim = (NN - row0 < 32 ? NN - row0 : 32) * 64;
    for (int i = tid; i < 32 * 64; i += 256) {
        float v = (i < lim) ? hin[(size_t)row0 * 64 + i] : 0.f;
        int row = i >> 6, k = i & 63;
        hs[k * 32 + row] = v;
    }
    __syncthreads();
    float accL[32], accR[32];
#pragma unroll
    for (int j = 0; j < 32; ++j) { accL[j] = 0.f; accR[j] = 0.f; }
    for (int k = 0; k < 64; ++k) {
        float wl = Wl[k * 256 + tid];
        float wr = Wr[k * 256 + tid];
#pragma unroll
        for (int j4 = 0; j4 < 8; ++j4) {
            const float4 hv = *reinterpret_cast<const float4*>(&hs[k * 32 + j4 * 4]);
            accL[j4*4+0] = fmaf(hv.x, wl, accL[j4*4+0]);
            accL[j4*4+1] = fmaf(hv.y, wl, accL[j4*4+1]);
            accL[j4*4+2] = fmaf(hv.z, wl, accL[j4*4+2]);
            accL[j4*4+3] = fmaf(hv.w, wl, accL[j4*4+3]);
            accR[j4*4+0] = fmaf(hv.x, wr, accR[j4*4+0]);
            accR[j4*4+1] = fmaf(hv.y, wr, accR[j4*4+1]);
            accR[j4*4+2] = fmaf(hv.z, wr, accR[j4*4+2]);
            accR[j4*4+3] = fmaf(hv.w, wr, accR[j4*4+3]);
        }
    }
    float bL = bl[tid], bR = br[tid];
    int nrows = NN - row0 < 32 ? NN - row0 : 32;
    for (int j = 0; j < nrows; ++j) {
        XL[((size_t)(row0 + j)) * 256 + tid] = accL[j] + bL;
        XR[((size_t)(row0 + j)) * 256 + tid] = accR[j] + bR;
    }
}

// ---------------- edge pass 1: logits + segment max ----------------
__global__ void pass1_kernel(const int* __restrict__ eidx, const float* __restrict__ eattr,
                             const int* __restrict__ eids, const int* __restrict__ cnt, int r,
                             const float* __restrict__ We, const float* __restrict__ att,
                             const float* __restrict__ ebase,
                             const float* __restrict__ XL, const float* __restrict__ XR,
                             float* __restrict__ elog, float* __restrict__ mbuf) {
    __shared__ float4 we_s[16 * 64];
    __shared__ float4 att_s[64];
    __shared__ float4 eb_s[64];
    int tid = threadIdx.x;
    for (int i = tid; i < 16 * 256; i += 256) {
        int k = i >> 8, j = i & 255;
        ((float*)we_s)[i] = We[((size_t)(r * 24 + k)) * 256 + j];
    }
    ((float*)att_s)[tid] = att[r * 256 + tid];
    ((float*)eb_s)[tid]  = ebase[r * 256 + tid];
    __syncthreads();
    int cntr = cnt[r];
    int wave = (blockIdx.x << 2) + (tid >> 6);
    int lane = tid & 63;
    int nw = gridDim.x << 2;
    for (int i = wave; i < cntr; i += nw) {
        int e = eids[r * EE + i];
        int src = eidx[e], dst = eidx[EE + e];
        float ea[16];
#pragma unroll
        for (int k = 0; k < 16; ++k) ea[k] = eattr[(size_t)e * 16 + k];
        const float4 xl = *reinterpret_cast<const float4*>(XL + (size_t)src * 256 + lane * 4);
        const float4 xr = *reinterpret_cast<const float4*>(XR + (size_t)dst * 256 + lane * 4);
        float4 ev = eb_s[lane];
#pragma unroll
        for (int k = 0; k < 16; ++k) {
            float4 w = we_s[k * 64 + lane];
            ev.x = fmaf(ea[k], w.x, ev.x);
            ev.y = fmaf(ea[k], w.y, ev.y);
            ev.z = fmaf(ea[k], w.z, ev.z);
            ev.w = fmaf(ea[k], w.w, ev.w);
        }
        float4 z;
        z.x = lrelu(xl.x + xr.x + ev.x);
        z.y = lrelu(xl.y + xr.y + ev.y);
        z.z = lrelu(xl.z + xr.z + ev.z);
        z.w = lrelu(xl.w + xr.w + ev.w);
        float4 a4 = att_s[lane];
        float p = z.x * a4.x + z.y * a4.y + z.z * a4.z + z.w * a4.w;
        p += __shfl_xor(p, 1, 64);
        p += __shfl_xor(p, 2, 64);
        p += __shfl_xor(p, 4, 64);
        p += __shfl_xor(p, 8, 64);
        if ((lane & 15) == 0) {
            int hh = lane >> 4;
            elog[(size_t)e * 4 + hh] = p;
            atomicMaxF(mbuf + ((size_t)r * NN + dst) * 4 + hh, p);
        }
    }
}

// ---------------- edge pass 2: exp + denom ----------------
__global__ void pass2_kernel(const int* __restrict__ eidx, const int* __restrict__ eids,
                             const int* __restrict__ cnt, int r,
                             float* __restrict__ elog, const float* __restrict__ mbuf,
                             float* __restrict__ den) {
    int cntr = cnt[r];
    int tot = cntr * 4;
    for (int idx = blockIdx.x * blockDim.x + threadIdx.x; idx < tot;
         idx += gridDim.x * blockDim.x) {
        int i = idx >> 2, hh = idx & 3;
        int e = eids[r * EE + i];
        int dst = eidx[EE + e];
        size_t mi = ((size_t)r * NN + dst) * 4 + hh;
        float ex = expf(elog[(size_t)e * 4 + hh] - mbuf[mi]);
        elog[(size_t)e * 4 + hh] = ex;
        atomicAdd(den + mi, ex);
    }
}

// ---------------- edge pass 3: weighted scatter ----------------
__global__ void pass3_kernel(const int* __restrict__ eidx, const int* __restrict__ eids,
                             const int* __restrict__ cnt, int r,
                             const float* __restrict__ elog, const float* __restrict__ den,
                             const float* __restrict__ gate,
                             const float* __restrict__ XL, float* __restrict__ hmsg) {
    int cntr = cnt[r];
    float coef = 0.25f * gate[r];
    int wave = (blockIdx.x << 2) + (threadIdx.x >> 6);
    int lane = threadIdx.x & 63;
    int nw = gridDim.x << 2;
    for (int i = wave; i < cntr; i += nw) {
        int e = eids[r * EE + i];
        int src = eidx[e], dst = eidx[EE + e];
        size_t mb = ((size_t)r * NN + dst) * 4;
        float a0 = elog[(size_t)e * 4 + 0] / (den[mb + 0] + 1e-16f);
        float a1 = elog[(size_t)e * 4 + 1] / (den[mb + 1] + 1e-16f);
        float a2 = elog[(size_t)e * 4 + 2] / (den[mb + 2] + 1e-16f);
        float a3 = elog[(size_t)e * 4 + 3] / (den[mb + 3] + 1e-16f);
        const float* xlp = XL + (size_t)src * 256;
        float val = a0 * xlp[lane] + a1 * xlp[64 + lane] +
                    a2 * xlp[128 + lane] + a3 * xlp[192 + lane];
        atomicAdd(hmsg + (size_t)dst * 64 + lane, coef * val);
    }
}

// ---------------- layer norm (H=64, wave per row) ----------------
__global__ void ln_kernel(const float* __restrict__ a, const float* __restrict__ badd,
                          const float* __restrict__ biasvec,
                          const float* __restrict__ g, const float* __restrict__ b,
                          float* __restrict__ out) {
    int row = blockIdx.x * 4 + (threadIdx.x >> 6);
    int l = threadIdx.x & 63;
    if (row >= NN) return;
    float v = a[(size_t)row * 64 + l] + badd[(size_t)row * 64 + l];
    if (biasvec) v += biasvec[l];
    float s = v;
#pragma unroll
    for (int mm = 1; mm < 64; mm <<= 1) s += __shfl_xor(s, mm, 64);
    float mu = s * (1.f / 64.f);
    float d = v - mu;
    float s2 = d * d;
#pragma unroll
    for (int mm = 1; mm < 64; mm <<= 1) s2 += __shfl_xor(s2, mm, 64);
    float var = s2 * (1.f / 64.f);
    out[(size_t)row * 64 + l] = d * rsqrtf(var + 1e-5f) * g[l] + b[l];
}

// ---------------- KAN layer (fused silu-base + spline GEMM) ----------------
template <int IN, int FOUT, int TILE>
__global__ __launch_bounds__(256) void kan_kernel(const float* __restrict__ Xin,
                                                  const float* __restrict__ Wt,
                                                  const float* __restrict__ grid,
                                                  float* __restrict__ Yout) {
    constexpr int DTOT = IN * 9;           // IN silu + IN*8 spline
    constexpr int GRP = 256 / FOUT;
    constexpr int RPG = TILE / GRP;
    __shared__ float act[TILE * DTOT];
    __shared__ float gs[12];
    __shared__ float invA[30], invB[30];
    int tid = threadIdx.x;
    if (tid < 12) gs[tid] = grid[tid];
    __syncthreads();
    if (tid < 30) {
        int k = tid / 10 + 1, j = tid % 10;
        if (j + k < 11) {
            invA[tid] = 1.f / (gs[j + k] - gs[j]);
            invB[tid] = 1.f / (gs[j + k + 1] - gs[j + 1]);
        }
    }
    __syncthreads();
    int row0 = blockIdx.x * TILE;
    for (int s = tid; s < TILE * IN; s += 256) {
        int row = s / IN, i = s % IN;
        int n = row0 + row;
        float x = (n < NN) ? Xin[(size_t)n * IN + i] : 0.f;
        float sig = 1.f / (1.f + expf(-x));
        act[row * DTOT + i] = x * sig;
        float bb[11];
#pragma unroll
        for (int j = 0; j < 11; ++j)
            bb[j] = (x >= gs[j] && x < gs[j + 1]) ? 1.f : 0.f;
#pragma unroll
        for (int k = 1; k <= 3; ++k) {
#pragma unroll
            for (int j = 0; j + k < 11; ++j)
                bb[j] = (x - gs[j]) * invA[(k - 1) * 10 + j] * bb[j] +
                        (gs[j + k + 1] - x) * invB[(k - 1) * 10 + j] * bb[j + 1];
        }
        float4 s0 = make_float4(bb[0], bb[1], bb[2], bb[3]);
        float4 s1 = make_float4(bb[4], bb[5], bb[6], bb[7]);
        *reinterpret_cast<float4*>(&act[row * DTOT + IN + i * 8])     = s0;
        *reinterpret_cast<float4*>(&act[row * DTOT + IN + i * 8 + 4]) = s1;
    }
    __syncthreads();
    int f = tid % FOUT;
    int grp = tid / FOUT;
    float acc[RPG];
#pragma unroll
    for (int rr = 0; rr < RPG; ++rr) acc[rr] = 0.f;
    for (int d4 = 0; d4 < DTOT / 4; ++d4) {
        float w0 = Wt[(size_t)(d4 * 4 + 0) * FOUT + f];
        float w1 = Wt[(size_t)(d4 * 4 + 1) * FOUT + f];
        float w2 = Wt[(size_t)(d4 * 4 + 2) * FOUT + f];
        float w3 = Wt[(size_t)(d4 * 4 + 3) * FOUT + f];
#pragma unroll
        for (int rr = 0; rr < RPG; ++rr) {
            const float4 av = *reinterpret_cast<const float4*>(
                &act[(grp * RPG + rr) * DTOT + d4 * 4]);
            acc[rr] = fmaf(av.x, w0, acc[rr]);
            acc[rr] = fmaf(av.y, w1, acc[rr]);
            acc[rr] = fmaf(av.z, w2, acc[rr]);
            acc[rr] = fmaf(av.w, w3, acc[rr]);
        }
    }
#pragma unroll
    for (int rr = 0; rr < RPG; ++rr) {
        int n = row0 + grp * RPG + rr;
        if (n < NN) Yout[(size_t)n * FOUT + f] = acc[rr];
    }
}

// ---------------- host launcher ----------------
extern "C" void kernel_launch(void* const* d_in, const int* in_sizes, int n_in,
                              void* d_out, int out_size, void* d_ws, size_t ws_size,
                              hipStream_t stream) {
    const float* h        = (const float*)d_in[0];
    const int*   eidx     = (const int*)d_in[1];
    const float* eattr    = (const float*)d_in[2];
    const int*   etype    = (const int*)d_in[3];
    const float* rel_emb  = (const float*)d_in[4];
    const float* rel_gate = (const float*)d_in[5];
    const float* Wl       = (const float*)d_in[6];
    const float* bl       = (const float*)d_in[7];
    const float* Wr       = (const float*)d_in[8];
    const float* br       = (const float*)d_in[9];
    const float* We       = (const float*)d_in[10];
    const float* be       = (const float*)d_in[11];
    const float* att      = (const float*)d_in[12];
    const float* out_bias = (const float*)d_in[13];
    const float* ln1_g    = (const float*)d_in[14];
    const float* ln1_b    = (const float*)d_in[15];
    const float* ln2_g    = (const float*)d_in[16];
    const float* ln2_b    = (const float*)d_in[17];
    const float* bw1      = (const float*)d_in[18];
    const float* sw1      = (const float*)d_in[19];
    const float* sc1      = (const float*)d_in[20];
    const float* grid1    = (const float*)d_in[21];
    const float* bw2      = (const float*)d_in[22];
    const float* sw2      = (const float*)d_in[23];
    const float* sc2      = (const float*)d_in[24];
    const float* grid2    = (const float*)d_in[25];
    float* out = (float*)d_out;
    float* W = (float*)d_ws;

    float* XL    = W + 0;
    float* XR    = W + 12800000;
    float* HM    = W + 25600000;
    float* M     = W + 28800000;
    float* DENb  = W + 29600000;
    float* EL    = W + 30400000;
    int*   EIDS  = (int*)(W + 32000000);
    int*   CNT   = (int*)(W + 33600000);
    float* GATE  = W + 33600064;
    float* BIAS  = W + 33600128;
    float* EBASE = W + 33600192;
    float* W1T   = W + 33601216;
    float* W2T   = W + 33674944;
    float* X  = W + 0;        // overlays XL (dead after relation loop)
    float* Y1 = W + 3200000;
    float* Y2 = W + 9600000;

    prep_small<<<1, 256, 0, stream>>>(rel_gate, out_bias, rel_emb, We, be,
                                      GATE, BIAS, EBASE, CNT);
    prep_wt<<<576, 256, 0, stream>>>(bw1, sw1, sc1, bw2, sw2, sc2, W1T, W2T);
    fill_init<<<2048, 256, 0, stream>>>(HM, M, DENb);
    bucket_fill<<<(EE + 255) / 256, 256, 0, stream>>>(etype, CNT, EIDS);

    for (int r = 0; r < 4; ++r) {
        gemm_xlxr<<<(NN + 31) / 32, 256, 0, stream>>>(
            h, Wl + (size_t)r * 64 * 256, bl + r * 256,
            Wr + (size_t)r * 64 * 256, br + r * 256, XL, XR);
        pass1_kernel<<<1024, 256, 0, stream>>>(eidx, eattr, EIDS, CNT, r, We, att,
                                               EBASE, XL, XR, EL, M);
        pass2_kernel<<<1024, 256, 0, stream>>>(eidx, EIDS, CNT, r, EL, M, DENb);
        pass3_kernel<<<1024, 256, 0, stream>>>(eidx, EIDS, CNT, r, EL, DENb, GATE,
                                               XL, HM);
    }

    ln_kernel<<<(NN + 3) / 4, 256, 0, stream>>>(h, HM, BIAS, ln1_g, ln1_b, X);
    kan_kernel<64, 128, 32><<<(NN + 31) / 32, 256, 0, stream>>>(X, W1T, grid1, Y1);
    kan_kernel<128, 64, 16><<<(NN + 15) / 16, 256, 0, stream>>>(Y1, W2T, grid2, Y2);
    ln_kernel<<<(NN + 3) / 4, 256, 0, stream>>>(X, Y2, nullptr, ln2_g, ln2_b, out);
}

// Round 3
// 1334.578 us; speedup vs baseline: 2.6585x; 2.6585x over previous
//
#include <hip/hip_runtime.h>
#include <math.h>

#define DEV __device__ __forceinline__

constexpr int NN   = 50000;   // nodes
constexpr int EE   = 400000;  // edges
constexpr int NB   = (EE + 255) / 256;  // 1563 bucket blocks
// H=64, HEADS=4, OUT=64 -> 256 cols per transform
// KAN: K=8 bases, GPTS=12 grid points, ORDER=3

// ---------------- workspace layout (float offsets) ----------------
// XL   : 0          .. 12.8M   (N*256)   [reused later: X, Y1, Y2]
// XR   : 12.8M      .. 25.6M   (N*256)   [head reused during bucketing: BC/BB]
// HMSG : 25.6M      .. 28.8M   (N*64)
// M    : 28.8M      .. 29.6M   (N*R*4)
// DEN  : 29.6M      .. 30.4M   (N*R*4)
// ELOG : 30.4M      .. 32.0M   (E*4)
// EIDS : 32.0M      .. 33.6M   (R*E ints)
// CNT  : 33.6M      (+64)
// GATE : 33.600064M (4), BIAS: 33.600128M (64), EBASE: 33.600192M (1024)
// W1T  : 33.601216M (73728), W2T: 33.674944M (73728)  -> total ~135 MB

DEV void atomicMaxF(float* addr, float val) {
    int iv = __float_as_int(val);
    if (iv >= 0) atomicMax((int*)addr, iv);
    else         atomicMin((unsigned int*)addr, __float_as_uint(val));
}

DEV float lrelu(float v) { return v >= 0.f ? v : 0.2f * v; }

// ---------------- prep kernels ----------------
__global__ void prep_small(const float* __restrict__ rel_gate,
                           const float* __restrict__ out_bias,
                           const float* __restrict__ rel_emb,
                           const float* __restrict__ We,
                           const float* __restrict__ be,
                           float* __restrict__ gate, float* __restrict__ biasvec,
                           float* __restrict__ ebase) {
    __shared__ float gs[4];
    int tid = threadIdx.x;
    if (tid == 0) {
        float g0 = rel_gate[0], g1 = rel_gate[1], g2 = rel_gate[2], g3 = rel_gate[3];
        float mx = fmaxf(fmaxf(g0, g1), fmaxf(g2, g3));
        float e0 = expf(g0 - mx), e1 = expf(g1 - mx), e2 = expf(g2 - mx), e3 = expf(g3 - mx);
        float s = e0 + e1 + e2 + e3;
        gs[0] = e0 / s; gs[1] = e1 / s; gs[2] = e2 / s; gs[3] = e3 / s;
        gate[0] = gs[0]; gate[1] = gs[1]; gate[2] = gs[2]; gate[3] = gs[3];
    }
    __syncthreads();
    if (tid < 64) {
        float b = 0.f;
        for (int r = 0; r < 4; ++r) b += gs[r] * out_bias[r * 64 + tid];
        biasvec[tid] = b;
    }
    // ebase[r][j] = be[r][j] + sum_i rel_emb[r][i] * We[r][16+i][j]
    for (int r = 0; r < 4; ++r) {
        float v = be[r * 256 + tid];
        for (int i = 0; i < 8; ++i)
            v += rel_emb[r * 8 + i] * We[((size_t)(r * 24 + 16 + i)) * 256 + tid];
        ebase[r * 256 + tid] = v;
    }
}

__global__ void prep_wt(const float* __restrict__ bw1, const float* __restrict__ sw1,
                        const float* __restrict__ sc1,
                        const float* __restrict__ bw2, const float* __restrict__ sw2,
                        const float* __restrict__ sc2,
                        float* __restrict__ W1T, float* __restrict__ W2T) {
    int idx = blockIdx.x * blockDim.x + threadIdx.x;
    const int tot1 = 576 * 128;
    const int tot  = tot1 + 1152 * 64;
    for (; idx < tot; idx += gridDim.x * blockDim.x) {
        if (idx < tot1) {
            int d = idx / 128, f = idx % 128;
            float v;
            if (d < 64) v = bw1[f * 64 + d];
            else { int ii = (d - 64) >> 3, kk = (d - 64) & 7;
                   v = sw1[(f * 64 + ii) * 8 + kk] * sc1[f * 64 + ii]; }
            W1T[idx] = v;
        } else {
            int j = idx - tot1;
            int d = j / 64, f = j % 64;
            float v;
            if (d < 128) v = bw2[f * 128 + d];
            else { int ii = (d - 128) >> 3, kk = (d - 128) & 7;
                   v = sw2[(f * 128 + ii) * 8 + kk] * sc2[f * 128 + ii]; }
            W2T[j] = v;
        }
    }
}

__global__ void fill_init(float* __restrict__ hmsg, float* __restrict__ m,
                          float* __restrict__ den) {
    const int n1 = NN * 64, n2 = NN * 16;
    const int tot = n1 + n2 + n2;
    for (int i = blockIdx.x * blockDim.x + threadIdx.x; i < tot;
         i += gridDim.x * blockDim.x) {
        if (i < n1) hmsg[i] = 0.f;
        else if (i < n1 + n2) m[i - n1] = -3.402823466e38f;
        else den[i - n1 - n2] = 0.f;
    }
}

// ---------------- bucketing: histogram + scan + scatter ----------------
__global__ void count_hist(const int* __restrict__ etype, int* __restrict__ bc) {
    __shared__ int lc[4];
    int tid = threadIdx.x;
    if (tid < 4) lc[tid] = 0;
    __syncthreads();
    int e = blockIdx.x * 256 + tid;
    if (e < EE) atomicAdd(&lc[etype[e]], 1);
    __syncthreads();
    if (tid < 4) bc[blockIdx.x * 4 + tid] = lc[tid];
}

__global__ void scan_blocks(const int* __restrict__ bc, int* __restrict__ bbase,
                            int* __restrict__ cnt) {
    // 256 threads: wave w handles relation w
    int w = threadIdx.x >> 6, lane = threadIdx.x & 63;
    int running = 0;
    for (int b0 = 0; b0 < NB; b0 += 64) {
        int b = b0 + lane;
        int v = (b < NB) ? bc[b * 4 + w] : 0;
        int s = v;
#pragma unroll
        for (int off = 1; off < 64; off <<= 1) {
            int t = __shfl_up(s, off, 64);
            if (lane >= off) s += t;
        }
        if (b < NB) bbase[b * 4 + w] = running + s - v;  // exclusive prefix
        running += __shfl(s, 63, 64);
    }
    if (lane == 0) cnt[w] = running;
}

__global__ void scatter_kernel(const int* __restrict__ etype,
                               const int* __restrict__ bbase,
                               int* __restrict__ eids) {
    __shared__ int lbase[4], lofs[4];
    int tid = threadIdx.x;
    if (tid < 4) { lbase[tid] = bbase[blockIdx.x * 4 + tid]; lofs[tid] = 0; }
    __syncthreads();
    int e = blockIdx.x * 256 + tid;
    if (e < EE) {
        int t = etype[e];
        int p = atomicAdd(&lofs[t], 1);
        eids[t * EE + lbase[t] + p] = e;
    }
}

// ---------------- per-relation node transforms ----------------
__global__ __launch_bounds__(256) void gemm_xlxr(
    const float* __restrict__ hin,
    const float* __restrict__ Wl, const float* __restrict__ bl,
    const float* __restrict__ Wr, const float* __restrict__ br,
    float* __restrict__ XL, float* __restrict__ XR) {
    __shared__ float hs[64 * 32];   // transposed: hs[k][row]
    int tid = threadIdx.x;
    int row0 = blockIdx.x * 32;
    int lim = (NN - row0 < 32 ? NN - row0 : 32) * 64;
    for (int i = tid; i < 32 * 64; i += 256) {
        float v = (i < lim) ? hin[(size_t)row0 * 64 + i] : 0.f;
        int row = i >> 6, k = i & 63;
        hs[k * 32 + row] = v;
    }
    __syncthreads();
    float accL[32], accR[32];
#pragma unroll
    for (int j = 0; j < 32; ++j) { accL[j] = 0.f; accR[j] = 0.f; }
    for (int k = 0; k < 64; ++k) {
        float wl = Wl[k * 256 + tid];
        float wr = Wr[k * 256 + tid];
#pragma unroll
        for (int j4 = 0; j4 < 8; ++j4) {
            const float4 hv = *reinterpret_cast<const float4*>(&hs[k * 32 + j4 * 4]);
            accL[j4*4+0] = fmaf(hv.x, wl, accL[j4*4+0]);
            accL[j4*4+1] = fmaf(hv.y, wl, accL[j4*4+1]);
            accL[j4*4+2] = fmaf(hv.z, wl, accL[j4*4+2]);
            accL[j4*4+3] = fmaf(hv.w, wl, accL[j4*4+3]);
            accR[j4*4+0] = fmaf(hv.x, wr, accR[j4*4+0]);
            accR[j4*4+1] = fmaf(hv.y, wr, accR[j4*4+1]);
            accR[j4*4+2] = fmaf(hv.z, wr, accR[j4*4+2]);
            accR[j4*4+3] = fmaf(hv.w, wr, accR[j4*4+3]);
        }
    }
    float bL = bl[tid], bR = br[tid];
    int nrows = NN - row0 < 32 ? NN - row0 : 32;
    for (int j = 0; j < nrows; ++j) {
        XL[((size_t)(row0 + j)) * 256 + tid] = accL[j] + bL;
        XR[((size_t)(row0 + j)) * 256 + tid] = accR[j] + bR;
    }
}

// ---------------- edge pass 1: logits + segment max ----------------
__global__ void pass1_kernel(const int* __restrict__ eidx, const float* __restrict__ eattr,
                             const int* __restrict__ eids, const int* __restrict__ cnt, int r,
                             const float* __restrict__ We, const float* __restrict__ att,
                             const float* __restrict__ ebase,
                             const float* __restrict__ XL, const float* __restrict__ XR,
                             float* __restrict__ elog, float* __restrict__ mbuf) {
    __shared__ float4 we_s[16 * 64];
    __shared__ float4 att_s[64];
    __shared__ float4 eb_s[64];
    int tid = threadIdx.x;
    for (int i = tid; i < 16 * 256; i += 256) {
        int k = i >> 8, j = i & 255;
        ((float*)we_s)[i] = We[((size_t)(r * 24 + k)) * 256 + j];
    }
    ((float*)att_s)[tid] = att[r * 256 + tid];
    ((float*)eb_s)[tid]  = ebase[r * 256 + tid];
    __syncthreads();
    int cntr = cnt[r];
    int wave = (blockIdx.x << 2) + (tid >> 6);
    int lane = tid & 63;
    int nw = gridDim.x << 2;
    for (int i = wave; i < cntr; i += nw) {
        int e = eids[r * EE + i];
        int src = eidx[e], dst = eidx[EE + e];
        float ea[16];
#pragma unroll
        for (int k = 0; k < 16; ++k) ea[k] = eattr[(size_t)e * 16 + k];
        const float4 xl = *reinterpret_cast<const float4*>(XL + (size_t)src * 256 + lane * 4);
        const float4 xr = *reinterpret_cast<const float4*>(XR + (size_t)dst * 256 + lane * 4);
        float4 ev = eb_s[lane];
#pragma unroll
        for (int k = 0; k < 16; ++k) {
            float4 w = we_s[k * 64 + lane];
            ev.x = fmaf(ea[k], w.x, ev.x);
            ev.y = fmaf(ea[k], w.y, ev.y);
            ev.z = fmaf(ea[k], w.z, ev.z);
            ev.w = fmaf(ea[k], w.w, ev.w);
        }
        float4 z;
        z.x = lrelu(xl.x + xr.x + ev.x);
        z.y = lrelu(xl.y + xr.y + ev.y);
        z.z = lrelu(xl.z + xr.z + ev.z);
        z.w = lrelu(xl.w + xr.w + ev.w);
        float4 a4 = att_s[lane];
        float p = z.x * a4.x + z.y * a4.y + z.z * a4.z + z.w * a4.w;
        p += __shfl_xor(p, 1, 64);
        p += __shfl_xor(p, 2, 64);
        p += __shfl_xor(p, 4, 64);
        p += __shfl_xor(p, 8, 64);
        if ((lane & 15) == 0) {
            int hh = lane >> 4;
            elog[(size_t)e * 4 + hh] = p;
            atomicMaxF(mbuf + ((size_t)r * NN + dst) * 4 + hh, p);
        }
    }
}

// ---------------- edge pass 2: exp + denom ----------------
__global__ void pass2_kernel(const int* __restrict__ eidx, const int* __restrict__ eids,
                             const int* __restrict__ cnt, int r,
                             float* __restrict__ elog, const float* __restrict__ mbuf,
                             float* __restrict__ den) {
    int cntr = cnt[r];
    int tot = cntr * 4;
    for (int idx = blockIdx.x * blockDim.x + threadIdx.x; idx < tot;
         idx += gridDim.x * blockDim.x) {
        int i = idx >> 2, hh = idx & 3;
        int e = eids[r * EE + i];
        int dst = eidx[EE + e];
        size_t mi = ((size_t)r * NN + dst) * 4 + hh;
        float ex = expf(elog[(size_t)e * 4 + hh] - mbuf[mi]);
        elog[(size_t)e * 4 + hh] = ex;
        atomicAdd(den + mi, ex);
    }
}

// ---------------- edge pass 3: weighted scatter ----------------
__global__ void pass3_kernel(const int* __restrict__ eidx, const int* __restrict__ eids,
                             const int* __restrict__ cnt, int r,
                             const float* __restrict__ elog, const float* __restrict__ den,
                             const float* __restrict__ gate,
                             const float* __restrict__ XL, float* __restrict__ hmsg) {
    int cntr = cnt[r];
    float coef = 0.25f * gate[r];
    int wave = (blockIdx.x << 2) + (threadIdx.x >> 6);
    int lane = threadIdx.x & 63;
    int nw = gridDim.x << 2;
    for (int i = wave; i < cntr; i += nw) {
        int e = eids[r * EE + i];
        int src = eidx[e], dst = eidx[EE + e];
        size_t mb = ((size_t)r * NN + dst) * 4;
        float a0 = elog[(size_t)e * 4 + 0] / (den[mb + 0] + 1e-16f);
        float a1 = elog[(size_t)e * 4 + 1] / (den[mb + 1] + 1e-16f);
        float a2 = elog[(size_t)e * 4 + 2] / (den[mb + 2] + 1e-16f);
        float a3 = elog[(size_t)e * 4 + 3] / (den[mb + 3] + 1e-16f);
        const float* xlp = XL + (size_t)src * 256;
        float val = a0 * xlp[lane] + a1 * xlp[64 + lane] +
                    a2 * xlp[128 + lane] + a3 * xlp[192 + lane];
        atomicAdd(hmsg + (size_t)dst * 64 + lane, coef * val);
    }
}

// ---------------- layer norm (H=64, wave per row) ----------------
__global__ void ln_kernel(const float* __restrict__ a, const float* __restrict__ badd,
                          const float* __restrict__ biasvec,
                          const float* __restrict__ g, const float* __restrict__ b,
                          float* __restrict__ out) {
    int row = blockIdx.x * 4 + (threadIdx.x >> 6);
    int l = threadIdx.x & 63;
    if (row >= NN) return;
    float v = a[(size_t)row * 64 + l] + badd[(size_t)row * 64 + l];
    if (biasvec) v += biasvec[l];
    float s = v;
#pragma unroll
    for (int mm = 1; mm < 64; mm <<= 1) s += __shfl_xor(s, mm, 64);
    float mu = s * (1.f / 64.f);
    float d = v - mu;
    float s2 = d * d;
#pragma unroll
    for (int mm = 1; mm < 64; mm <<= 1) s2 += __shfl_xor(s2, mm, 64);
    float var = s2 * (1.f / 64.f);
    out[(size_t)row * 64 + l] = d * rsqrtf(var + 1e-5f) * g[l] + b[l];
}

// ---------------- KAN layer (fused silu-base + spline GEMM) ----------------
template <int IN, int FOUT, int TILE>
__global__ __launch_bounds__(256) void kan_kernel(const float* __restrict__ Xin,
                                                  const float* __restrict__ Wt,
                                                  const float* __restrict__ grid,
                                                  float* __restrict__ Yout) {
    constexpr int DTOT = IN * 9;           // IN silu + IN*8 spline
    constexpr int GRP = 256 / FOUT;
    constexpr int RPG = TILE / GRP;
    __shared__ float act[TILE * DTOT];
    __shared__ float gs[12];
    __shared__ float invA[30], invB[30];
    int tid = threadIdx.x;
    if (tid < 12) gs[tid] = grid[tid];
    __syncthreads();
    if (tid < 30) {
        int k = tid / 10 + 1, j = tid % 10;
        if (j + k < 11) {
            invA[tid] = 1.f / (gs[j + k] - gs[j]);
            invB[tid] = 1.f / (gs[j + k + 1] - gs[j + 1]);
        }
    }
    __syncthreads();
    int row0 = blockIdx.x * TILE;
    for (int s = tid; s < TILE * IN; s += 256) {
        int row = s / IN, i = s % IN;
        int n = row0 + row;
        float x = (n < NN) ? Xin[(size_t)n * IN + i] : 0.f;
        float sig = 1.f / (1.f + expf(-x));
        act[row * DTOT + i] = x * sig;
        float bb[11];
#pragma unroll
        for (int j = 0; j < 11; ++j)
            bb[j] = (x >= gs[j] && x < gs[j + 1]) ? 1.f : 0.f;
#pragma unroll
        for (int k = 1; k <= 3; ++k) {
#pragma unroll
            for (int j = 0; j + k < 11; ++j)
                bb[j] = (x - gs[j]) * invA[(k - 1) * 10 + j] * bb[j] +
                        (gs[j + k + 1] - x) * invB[(k - 1) * 10 + j] * bb[j + 1];
        }
        float4 s0 = make_float4(bb[0], bb[1], bb[2], bb[3]);
        float4 s1 = make_float4(bb[4], bb[5], bb[6], bb[7]);
        *reinterpret_cast<float4*>(&act[row * DTOT + IN + i * 8])     = s0;
        *reinterpret_cast<float4*>(&act[row * DTOT + IN + i * 8 + 4]) = s1;
    }
    __syncthreads();
    int f = tid % FOUT;
    int grp = tid / FOUT;
    float acc[RPG];
#pragma unroll
    for (int rr = 0; rr < RPG; ++rr) acc[rr] = 0.f;
    for (int d4 = 0; d4 < DTOT / 4; ++d4) {
        float w0 = Wt[(size_t)(d4 * 4 + 0) * FOUT + f];
        float w1 = Wt[(size_t)(d4 * 4 + 1) * FOUT + f];
        float w2 = Wt[(size_t)(d4 * 4 + 2) * FOUT + f];
        float w3 = Wt[(size_t)(d4 * 4 + 3) * FOUT + f];
#pragma unroll
        for (int rr = 0; rr < RPG; ++rr) {
            const float4 av = *reinterpret_cast<const float4*>(
                &act[(grp * RPG + rr) * DTOT + d4 * 4]);
            acc[rr] = fmaf(av.x, w0, acc[rr]);
            acc[rr] = fmaf(av.y, w1, acc[rr]);
            acc[rr] = fmaf(av.z, w2, acc[rr]);
            acc[rr] = fmaf(av.w, w3, acc[rr]);
        }
    }
#pragma unroll
    for (int rr = 0; rr < RPG; ++rr) {
        int n = row0 + grp * RPG + rr;
        if (n < NN) Yout[(size_t)n * FOUT + f] = acc[rr];
    }
}

// ---------------- host launcher ----------------
extern "C" void kernel_launch(void* const* d_in, const int* in_sizes, int n_in,
                              void* d_out, int out_size, void* d_ws, size_t ws_size,
                              hipStream_t stream) {
    const float* h        = (const float*)d_in[0];
    const int*   eidx     = (const int*)d_in[1];
    const float* eattr    = (const float*)d_in[2];
    const int*   etype    = (const int*)d_in[3];
    const float* rel_emb  = (const float*)d_in[4];
    const float* rel_gate = (const float*)d_in[5];
    const float* Wl       = (const float*)d_in[6];
    const float* bl       = (const float*)d_in[7];
    const float* Wr       = (const float*)d_in[8];
    const float* br       = (const float*)d_in[9];
    const float* We       = (const float*)d_in[10];
    const float* be       = (const float*)d_in[11];
    const float* att      = (const float*)d_in[12];
    const float* out_bias = (const float*)d_in[13];
    const float* ln1_g    = (const float*)d_in[14];
    const float* ln1_b    = (const float*)d_in[15];
    const float* ln2_g    = (const float*)d_in[16];
    const float* ln2_b    = (const float*)d_in[17];
    const float* bw1      = (const float*)d_in[18];
    const float* sw1      = (const float*)d_in[19];
    const float* sc1      = (const float*)d_in[20];
    const float* grid1    = (const float*)d_in[21];
    const float* bw2      = (const float*)d_in[22];
    const float* sw2      = (const float*)d_in[23];
    const float* sc2      = (const float*)d_in[24];
    const float* grid2    = (const float*)d_in[25];
    float* out = (float*)d_out;
    float* W = (float*)d_ws;

    float* XL    = W + 0;
    float* XR    = W + 12800000;
    float* HM    = W + 25600000;
    float* M     = W + 28800000;
    float* DENb  = W + 29600000;
    float* EL    = W + 30400000;
    int*   EIDS  = (int*)(W + 32000000);
    int*   CNT   = (int*)(W + 33600000);
    float* GATE  = W + 33600064;
    float* BIAS  = W + 33600128;
    float* EBASE = W + 33600192;
    float* W1T   = W + 33601216;
    float* W2T   = W + 33674944;
    float* X  = W + 0;        // overlays XL (dead after relation loop)
    float* Y1 = W + 3200000;
    float* Y2 = W + 9600000;
    // bucketing scratch overlays XR head (dead until first gemm_xlxr,
    // stream ordering makes this safe)
    int* BC = (int*)(W + 12800000);           // NB*4 block histograms
    int* BB = (int*)(W + 12800000 + 8192);    // NB*4 block bases

    prep_small<<<1, 256, 0, stream>>>(rel_gate, out_bias, rel_emb, We, be,
                                      GATE, BIAS, EBASE);
    prep_wt<<<576, 256, 0, stream>>>(bw1, sw1, sc1, bw2, sw2, sc2, W1T, W2T);
    fill_init<<<2048, 256, 0, stream>>>(HM, M, DENb);
    count_hist<<<NB, 256, 0, stream>>>(etype, BC);
    scan_blocks<<<1, 256, 0, stream>>>(BC, BB, CNT);
    scatter_kernel<<<NB, 256, 0, stream>>>(etype, BB, EIDS);

    for (int r = 0; r < 4; ++r) {
        gemm_xlxr<<<(NN + 31) / 32, 256, 0, stream>>>(
            h, Wl + (size_t)r * 64 * 256, bl + r * 256,
            Wr + (size_t)r * 64 * 256, br + r * 256, XL, XR);
        pass1_kernel<<<1024, 256, 0, stream>>>(eidx, eattr, EIDS, CNT, r, We, att,
                                               EBASE, XL, XR, EL, M);
        pass2_kernel<<<1024, 256, 0, stream>>>(eidx, EIDS, CNT, r, EL, M, DENb);
        pass3_kernel<<<1024, 256, 0, stream>>>(eidx, EIDS, CNT, r, EL, DENb, GATE,
                                               XL, HM);
    }

    ln_kernel<<<(NN + 3) / 4, 256, 0, stream>>>(h, HM, BIAS, ln1_g, ln1_b, X);
    kan_kernel<64, 128, 32><<<(NN + 31) / 32, 256, 0, stream>>>(X, W1T, grid1, Y1);
    kan_kernel<128, 64, 16><<<(NN + 15) / 16, 256, 0, stream>>>(Y1, W2T, grid2, Y2);
    ln_kernel<<<(NN + 3) / 4, 256, 0, stream>>>(X, Y2, nullptr, ln2_g, ln2_b, out);
}